// Round 10
// baseline (213.766 us; speedup 1.0000x reference)
//
#include <hip/hip_runtime.h>
#include <hip/hip_bf16.h>

#define N_NODES 50000
#define N_EDGES 1600000
#define NREL    16
#define DIM     64

#define BKT_SZ  16            // fused2 dst-tile
#define NTILE   3125          // 50000/16
#define NSEG_AL 50049         // max seg index 50047 (cb=390,tl=7) + 1

#define CB_SH   7             // coarse bucket = dst>>7 (128 dsts)
#define NCB     391           // ceil(50000/128)
#define P1_CHUNK 2048
#define P1_GRID  782          // ceil(1.6M/2048)

#define CB_R_ARENA 5120       // R slots per coarse bucket (mean 4096 + 16s)
#define CB_ARENA 8704         // packed2 arena per cb: max run + 128*31 pad
#define EMAX    (NCB * CB_ARENA)   // 3,403,264 slots
#define PREP_HBLK 3125        // 3.2M h elems / 1024 per block

typedef __attribute__((ext_vector_type(8))) short short8;
typedef __attribute__((ext_vector_type(4))) float float4v;
typedef __attribute__((ext_vector_type(4))) unsigned short ushort4v;

template<int IS_F32>
__device__ __forceinline__ float ldx(const void* p, size_t i) {
    if (IS_F32) {
        return ((const float*)p)[i];
    } else {
        unsigned short u = ((const unsigned short*)p)[i];
        return __uint_as_float(((unsigned)u) << 16);
    }
}

__device__ __forceinline__ float bfbits2f(unsigned short u) {
    return __uint_as_float(((unsigned)u) << 16);
}

__device__ __forceinline__ unsigned short f2bfbits(float v) {
    __hip_bfloat16 b = __float2bfloat16(v);
    unsigned short us; __builtin_memcpy(&us, &b, 2);
    return us;
}

// ---------------------------------------------------------------------------
// Dtype detector (proven) + gcur zeroing.
// ---------------------------------------------------------------------------
__global__ __launch_bounds__(1024) void k_detect(
    const float* __restrict__ norm_f, int* __restrict__ flag,
    int* __restrict__ gcur)
{
    __shared__ int sbad;
    if (threadIdx.x == 0) sbad = 0;
    if (threadIdx.x < NCB) gcur[threadIdx.x] = 0;
    __syncthreads();
    float v = norm_f[threadIdx.x];
    int bad = (v != v || fabsf(v) > 1e3f) ? 1 : 0;
    if (bad) atomicOr(&sbad, 1);
    __syncthreads();
    if (threadIdx.x == 0) *flag = sbad ? 0 : 1;
}

// ---------------------------------------------------------------------------
// SPLIT+PREP (proven R9). hbf is now written in PERMUTED row layout:
// element c of a row lands at position (c&15)*4 + (c>>4), so fused2's
// per-lane B-fragment elements {n15, 16+n15, 32+n15, 48+n15} are one
// contiguous 8-B ushort4 — 1 gather instr/edge instead of 4.
// ---------------------------------------------------------------------------
template<int IS_F32>
__device__ __forceinline__ void split_body(
    const int* __restrict__ src, const int* __restrict__ dst,
    const int* __restrict__ rel, const void* __restrict__ norm_raw,
    int* __restrict__ gcur, unsigned long long* __restrict__ R,
    int* hist, int* curs)
{
    const int blk = blockIdx.x;
    for (int i = threadIdx.x; i < NCB; i += 256) hist[i] = 0;
    __syncthreads();
    const int e0 = blk * P1_CHUNK;
    for (int i = threadIdx.x; i < P1_CHUNK; i += 256) {
        int e = e0 + i;
        if (e < N_EDGES) atomicAdd(&hist[dst[e] >> CB_SH], 1);
    }
    __syncthreads();
    for (int b = threadIdx.x; b < NCB; b += 256) {
        int c = hist[b];
        if (c > 0) {
            int s = atomicAdd(&gcur[b], c);
            if (s + c > CB_R_ARENA) s = CB_R_ARENA - c;   // OOB guard
            curs[b] = b * CB_R_ARENA + s;
        }
    }
    __syncthreads();
    for (int i = threadIdx.x; i < P1_CHUNK; i += 256) {
        int e = e0 + i;
        if (e >= N_EDGES) continue;
        int d = dst[e];
        int pos = atomicAdd(&curs[d >> CB_SH], 1);
        unsigned short nb = f2bfbits(ldx<IS_F32>(norm_raw, e));
        unsigned long long rec =
              (unsigned long long)(d & 127)
            | ((unsigned long long)(unsigned)src[e] << 8)
            | ((unsigned long long)(unsigned)rel[e] << 24)
            | ((unsigned long long)nb << 32);
        R[pos] = rec;
    }
}

__global__ __launch_bounds__(256) void k_split_prep(
    const int* __restrict__ src, const int* __restrict__ dst,
    const int* __restrict__ rel, const void* __restrict__ norm_raw,
    int* __restrict__ gcur, unsigned long long* __restrict__ R,
    const void* __restrict__ h_raw, const void* __restrict__ w_raw,
    unsigned short* __restrict__ hbf, unsigned short* __restrict__ Wswz,
    const int* __restrict__ flag)
{
    __shared__ int hist[NCB];
    __shared__ int curs[NCB];
    const int blk = blockIdx.x;
    if (blk < P1_GRID) {
        if (*flag) split_body<1>(src, dst, rel, norm_raw, gcur, R, hist, curs);
        else       split_body<0>(src, dst, rel, norm_raw, gcur, R, hist, curs);
    } else {
        const int f = *flag;
        const int blk2 = blk - P1_GRID;
        if (blk2 < PREP_HBLK) {
            // 1024 elems = 16 rows per block; thread (rl, x) handles row
            // base+rl, cols {x, x+16, x+32, x+48} -> contiguous permuted
            // ushort4 at row*64 + 4x.
            const int x = threadIdx.x & 15, rl = threadIdx.x >> 4;
            const int row = blk2 * 16 + rl;
            const size_t rb = (size_t)row * 64;
            ushort4v o;
            if (f) {
                const float* hf = (const float*)h_raw;
                o[0] = f2bfbits(hf[rb + x]);
                o[1] = f2bfbits(hf[rb + x + 16]);
                o[2] = f2bfbits(hf[rb + x + 32]);
                o[3] = f2bfbits(hf[rb + x + 48]);
            } else {
                const unsigned short* hr = (const unsigned short*)h_raw;
                o[0] = hr[rb + x];
                o[1] = hr[rb + x + 16];
                o[2] = hr[rb + x + 32];
                o[3] = hr[rb + x + 48];
            }
            *(ushort4v*)(hbf + rb + 4 * x) = o;
        } else {
            int rel2 = blk2 - PREP_HBLK;
            for (int idx = threadIdx.x; idx < 4096; idx += 256) {
                int d = idx >> 6, o = idx & 63;
                float wv = f ? ((const float*)w_raw)[(size_t)((rel2 << 6) + d) * 64 + o]
                             : bfbits2f(((const unsigned short*)w_raw)[(size_t)((rel2 << 6) + d) * 64 + o]);
                int c = d >> 5, q = (d >> 3) & 3, j = d & 7;
                Wswz[(size_t)rel2 * 5120 + ((c << 6) + o) * 40 + q * 8 + j] = f2bfbits(wv);
            }
        }
    }
}

// ---------------------------------------------------------------------------
// FINE (proven R9): per-cb R run -> 128 (rel,tile) bins in the packed arena.
// ---------------------------------------------------------------------------
__global__ __launch_bounds__(256) void k_fine(
    const int* __restrict__ gcur,
    const unsigned long long* __restrict__ R,
    unsigned* __restrict__ packed2, unsigned short* __restrict__ normS,
    int* __restrict__ segBase, int* __restrict__ segCnt)
{
    __shared__ int cnt[128], sbl[128], curs[128];
    const int tid = threadIdx.x, cb = blockIdx.x;
    if (tid < 128) { cnt[tid] = 0; curs[tid] = 0; }
    __syncthreads();
    const int c0 = cb * CB_R_ARENA;
    const int c1 = c0 + min(gcur[cb], CB_R_ARENA);

    for (int i = c0 + tid; i < c1; i += 256) {
        unsigned long long rec = R[i];
        int bin = (int)((rec >> 24) & 15) * 8 + (int)((rec >> 4) & 7);
        atomicAdd(&cnt[bin], 1);
    }
    __syncthreads();

    if (tid == 0) {
        int g = cb * CB_ARENA;
        for (int j = 0; j < 128; ++j) {
            sbl[j] = g;
            g += (cnt[j] + 31) & ~31;
        }
    }
    __syncthreads();

    if (tid < 128) {
        int seg = ((cb * 8 + (tid & 7)) << 4) + (tid >> 3);   // tile*16 + rel
        segBase[seg] = sbl[tid];
        segCnt[seg]  = cnt[tid];
    }

    for (int i = c0 + tid; i < c1; i += 256) {
        unsigned long long rec = R[i];
        int bin = (int)((rec >> 24) & 15) * 8 + (int)((rec >> 4) & 7);
        int pos = sbl[bin] + atomicAdd(&curs[bin], 1);
        packed2[pos] = (unsigned)rec & 0x00FFFF0Fu;   // (dst&15) | (src<<8)
        normS[pos]   = (unsigned short)(rec >> 32);
    }
    __syncthreads();

    for (int p = tid; p < 128 * 32; p += 256) {
        int bin = p >> 5, j = p & 31;
        int c = cnt[bin], pe = (c + 31) & ~31;
        if (j < pe - c) {
            int pos = sbl[bin] + c + j;
            packed2[pos] = 0;
            normS[pos]   = 0;
        }
    }
}

// ---------------------------------------------------------------------------
// K_FUSED2 v5: R7-proven structure (2 waves/tile, rel halves, LDS merge)
// with the permuted-hbf gather: ONE ushort4 load per edge yields the lane's
// element for all four B-fragments (was 4 separate 2-B loads). Scattered
// VMEM instruction count drops ~4x — the cross-round evidence (k_acc and
// fused2 both ~60us at ~1.7M scattered VMEM instrs) says instr rate is
// the wall, not bandwidth.
// ---------------------------------------------------------------------------
#define MFMA_BF16 __builtin_amdgcn_mfma_f32_16x16x32_bf16

__global__ __launch_bounds__(256) void k_fused2(
    const unsigned* __restrict__ packed2,
    const unsigned short* __restrict__ normS,
    const unsigned short* __restrict__ hbf,
    const unsigned short* __restrict__ Wswz,
    const int* __restrict__ segBase,
    const int* __restrict__ segCnt,
    void* __restrict__ out, const int* __restrict__ flag)
{
    __shared__ __align__(16) unsigned short sbuf[4][16 * 72];
    __shared__ float pbuf[2][64][17];
    const int tid  = threadIdx.x;
    const int lane = tid & 63, wave = tid >> 6;
    const int n15  = lane & 15, quad = lane >> 4;
    const int tin  = wave >> 1;          // tile within block
    const int half = wave & 1;           // rel half
    const int tile = blockIdx.x * 2 + tin;
    const bool valid = (tile < NTILE);

    float4v ac0 = {0.f,0.f,0.f,0.f}, ac1 = {0.f,0.f,0.f,0.f};
    float4v ac2 = {0.f,0.f,0.f,0.f}, ac3 = {0.f,0.f,0.f,0.f};
    unsigned short* sb_ = &sbuf[wave][0];

    if (valid) {
        const int r0 = half * 8;
        for (int r = r0; r < r0 + 8; ++r) {
            const int sgb  = segBase[tile * 16 + r];
            const int scnt = segCnt[tile * 16 + r];
            if (scnt == 0) continue;
            const int nch = (scnt + 31) >> 5;

            float4v s0 = {0.f,0.f,0.f,0.f}, s1 = {0.f,0.f,0.f,0.f};
            float4v s2 = {0.f,0.f,0.f,0.f}, s3 = {0.f,0.f,0.f,0.f};

            for (int c = 0; c < nch; ++c) {
                const int e0 = sgb + (c << 5) + (quad << 3);
                const uint4 pa = *(const uint4*)(packed2 + e0);
                const uint4 pb = *(const uint4*)(packed2 + e0 + 4);
                const ushort4v na = *(const ushort4v*)(normS + e0);
                const ushort4v nb = *(const ushort4v*)(normS + e0 + 4);

                // one 8-B permuted gather per edge: v_j = cols
                // {n15,16+n15,32+n15,48+n15} of edge j's h row.
                const int co = 4 * n15;
                ushort4v v0 = *(const ushort4v*)(hbf + (size_t)(pa.x >> 8) * 64 + co);
                ushort4v v1 = *(const ushort4v*)(hbf + (size_t)(pa.y >> 8) * 64 + co);
                ushort4v v2 = *(const ushort4v*)(hbf + (size_t)(pa.z >> 8) * 64 + co);
                ushort4v v3 = *(const ushort4v*)(hbf + (size_t)(pa.w >> 8) * 64 + co);
                ushort4v v4 = *(const ushort4v*)(hbf + (size_t)(pb.x >> 8) * 64 + co);
                ushort4v v5 = *(const ushort4v*)(hbf + (size_t)(pb.y >> 8) * 64 + co);
                ushort4v v6 = *(const ushort4v*)(hbf + (size_t)(pb.z >> 8) * 64 + co);
                ushort4v v7 = *(const ushort4v*)(hbf + (size_t)(pb.w >> 8) * 64 + co);

                short8 av;
                av[0] = ((int)(pa.x & 15u) == n15) ? (short)na[0] : (short)0;
                av[1] = ((int)(pa.y & 15u) == n15) ? (short)na[1] : (short)0;
                av[2] = ((int)(pa.z & 15u) == n15) ? (short)na[2] : (short)0;
                av[3] = ((int)(pa.w & 15u) == n15) ? (short)na[3] : (short)0;
                av[4] = ((int)(pb.x & 15u) == n15) ? (short)nb[0] : (short)0;
                av[5] = ((int)(pb.y & 15u) == n15) ? (short)nb[1] : (short)0;
                av[6] = ((int)(pb.z & 15u) == n15) ? (short)nb[2] : (short)0;
                av[7] = ((int)(pb.w & 15u) == n15) ? (short)nb[3] : (short)0;

#define BV_MFMA(S, K) \
                { short8 bv; \
                  bv[0] = (short)v0[K]; bv[1] = (short)v1[K]; \
                  bv[2] = (short)v2[K]; bv[3] = (short)v3[K]; \
                  bv[4] = (short)v4[K]; bv[5] = (short)v5[K]; \
                  bv[6] = (short)v6[K]; bv[7] = (short)v7[K]; \
                  S = MFMA_BF16(av, bv, S, 0, 0, 0); }

                BV_MFMA(s0, 0)
                BV_MFMA(s1, 1)
                BV_MFMA(s2, 2)
                BV_MFMA(s3, 3)
#undef BV_MFMA
            }

            // repack s (C layout: row=quad*4+i, col=t*16+n15) -> LDS row-major
#pragma unroll
            for (int i = 0; i < 4; ++i) {
                sb_[(quad * 4 + i) * 72 +  0 + n15] = f2bfbits(s0[i]);
                sb_[(quad * 4 + i) * 72 + 16 + n15] = f2bfbits(s1[i]);
                sb_[(quad * 4 + i) * 72 + 32 + n15] = f2bfbits(s2[i]);
                sb_[(quad * 4 + i) * 72 + 48 + n15] = f2bfbits(s3[i]);
            }

            // A-frags: row=n15, k-chunk=quad (k1-proven layout)
            const short8 a0 = *(const short8*)(sb_ + n15 * 72 + quad * 8);
            const short8 a1 = *(const short8*)(sb_ + n15 * 72 + 32 + quad * 8);

            const unsigned short* wp = Wswz + (size_t)r * 5120;
            const short8 w00 = *(const short8*)(wp + ( 0 + n15) * 40 + quad * 8);
            const short8 w01 = *(const short8*)(wp + (16 + n15) * 40 + quad * 8);
            const short8 w02 = *(const short8*)(wp + (32 + n15) * 40 + quad * 8);
            const short8 w03 = *(const short8*)(wp + (48 + n15) * 40 + quad * 8);
            const short8 w10 = *(const short8*)(wp + (64 + n15) * 40 + quad * 8);
            const short8 w11 = *(const short8*)(wp + (80 + n15) * 40 + quad * 8);
            const short8 w12 = *(const short8*)(wp + (96 + n15) * 40 + quad * 8);
            const short8 w13 = *(const short8*)(wp + (112 + n15) * 40 + quad * 8);

            ac0 = MFMA_BF16(a0, w00, ac0, 0, 0, 0);
            ac1 = MFMA_BF16(a0, w01, ac1, 0, 0, 0);
            ac2 = MFMA_BF16(a0, w02, ac2, 0, 0, 0);
            ac3 = MFMA_BF16(a0, w03, ac3, 0, 0, 0);
            ac0 = MFMA_BF16(a1, w10, ac0, 0, 0, 0);
            ac1 = MFMA_BF16(a1, w11, ac1, 0, 0, 0);
            ac2 = MFMA_BF16(a1, w12, ac2, 0, 0, 0);
            ac3 = MFMA_BF16(a1, w13, ac3, 0, 0, 0);
        }
    }

    // merge rel halves: odd wave publishes, even wave reduces + stores.
    if (half) {
#pragma unroll
        for (int i = 0; i < 4; ++i) {
            pbuf[tin][lane][i]      = ac0[i];
            pbuf[tin][lane][4 + i]  = ac1[i];
            pbuf[tin][lane][8 + i]  = ac2[i];
            pbuf[tin][lane][12 + i] = ac3[i];
        }
    }
    __syncthreads();
    if (!half && valid) {
#pragma unroll
        for (int i = 0; i < 4; ++i) {
            ac0[i] += pbuf[tin][lane][i];
            ac1[i] += pbuf[tin][lane][4 + i];
            ac2[i] += pbuf[tin][lane][8 + i];
            ac3[i] += pbuf[tin][lane][12 + i];
        }
        const int node0 = tile << 4;
        const int f = *flag;
#define STORE_T(AC, T) \
        { \
            _Pragma("unroll") \
            for (int i = 0; i < 4; ++i) { \
                float rv = fmaxf(AC[i], 0.f); \
                size_t ob = (size_t)(node0 + quad * 4 + i) * 64 + (T) * 16 + n15; \
                if (f) ((float*)out)[ob] = rv; \
                else   ((unsigned short*)out)[ob] = f2bfbits(rv); \
            } \
        }
        STORE_T(ac0, 0)
        STORE_T(ac1, 1)
        STORE_T(ac2, 2)
        STORE_T(ac3, 3)
#undef STORE_T
    }
}

// ---------------------------------------------------------------------------
extern "C" void kernel_launch(void* const* d_in, const int* in_sizes, int n_in,
                              void* d_out, int out_size, void* d_ws, size_t ws_size,
                              hipStream_t stream)
{
    const void* h      = d_in[0];
    const void* weight = d_in[1];
    const void* norm   = d_in[2];
    const int* src = (const int*)d_in[3];
    const int* dst = (const int*)d_in[4];
    const int* rel = (const int*)d_in[5];

    char* w = (char*)d_ws;
    int* flag = (int*)w;                        w += 256;
    int* gcur = (int*)w;                        w += (NCB * 4 + 255) / 256 * 256;
    int* segBase = (int*)w;                     w += ((size_t)NSEG_AL * 4 + 255) / 256 * 256;
    int* segCnt  = (int*)w;                     w += ((size_t)NSEG_AL * 4 + 255) / 256 * 256;
    unsigned long long* R = (unsigned long long*)w;  w += (size_t)NCB * CB_R_ARENA * 8;
    unsigned* packed2 = (unsigned*)w;           w += ((size_t)EMAX * 4 + 255) / 256 * 256;
    unsigned short* normS = (unsigned short*)w; w += ((size_t)EMAX * 2 + 255) / 256 * 256;
    unsigned short* hbf = (unsigned short*)w;   w += (size_t)N_NODES * DIM * 2;
    unsigned short* Wswz = (unsigned short*)w;  w += (size_t)NREL * 5120 * 2;

    k_detect<<<1, 1024, 0, stream>>>((const float*)norm, flag, gcur);

    k_split_prep<<<P1_GRID + PREP_HBLK + NREL, 256, 0, stream>>>(
        src, dst, rel, norm, gcur, R, h, weight, hbf, Wswz, flag);

    k_fine<<<NCB, 256, 0, stream>>>(gcur, R, packed2, normS, segBase, segCnt);

    k_fused2<<<(NTILE + 1) / 2, 256, 0, stream>>>(packed2, normS, hbf, Wswz,
                                                  segBase, segCnt, d_out, flag);
}

// Round 12
// 180.261 us; speedup vs baseline: 1.1859x; 1.1859x over previous
//
#include <hip/hip_runtime.h>
#include <hip/hip_bf16.h>

#define N_NODES 50000
#define N_EDGES 1600000
#define NREL    16
#define DIM     64

#define NTILE   3125          // 50000/16

#define CB_SH   7             // coarse bucket = dst>>7 (128 dsts)
#define NCB     391           // ceil(50000/128)
#define P1_CHUNK 2048
#define P1_GRID  782          // ceil(1.6M/2048)

#define CB_R_ARENA 5120       // R slots per coarse bucket (mean 4092 + 16 sigma)
#define LBIN    6080          // LDS bin arena: 5120 + 128*7 align8 + 31 overread
#define PREP_HBLK 3125        // 3.2M h elems / 1024 per block

typedef __attribute__((ext_vector_type(8))) short short8;
typedef __attribute__((ext_vector_type(4))) float float4v;
typedef __attribute__((ext_vector_type(4))) unsigned short ushort4v;

template<int IS_F32>
__device__ __forceinline__ float ldx(const void* p, size_t i) {
    if (IS_F32) {
        return ((const float*)p)[i];
    } else {
        unsigned short u = ((const unsigned short*)p)[i];
        return __uint_as_float(((unsigned)u) << 16);
    }
}

__device__ __forceinline__ float bfbits2f(unsigned short u) {
    return __uint_as_float(((unsigned)u) << 16);
}

__device__ __forceinline__ unsigned short f2bfbits(float v) {
    __hip_bfloat16 b = __float2bfloat16(v);
    unsigned short us; __builtin_memcpy(&us, &b, 2);
    return us;
}

// ---------------------------------------------------------------------------
// Dtype detector (proven) + gcur zeroing.
// ---------------------------------------------------------------------------
__global__ __launch_bounds__(1024) void k_detect(
    const float* __restrict__ norm_f, int* __restrict__ flag,
    int* __restrict__ gcur)
{
    __shared__ int sbad;
    if (threadIdx.x == 0) sbad = 0;
    if (threadIdx.x < NCB) gcur[threadIdx.x] = 0;
    __syncthreads();
    float v = norm_f[threadIdx.x];
    int bad = (v != v || fabsf(v) > 1e3f) ? 1 : 0;
    if (bad) atomicOr(&sbad, 1);
    __syncthreads();
    if (threadIdx.x == 0) *flag = sbad ? 0 : 1;
}

// ---------------------------------------------------------------------------
// SPLIT+PREP (proven R9/R10): chunk LDS-hist -> one atomic reservation per
// (block,bucket) into fixed per-cb R arenas -> LDS-cursor placement.
// hbf written in PERMUTED row layout (R10-proven): element c of a row lands
// at (c&15)*4 + (c>>4), so a lane's 4 B-fragment elements are one ushort4.
// ---------------------------------------------------------------------------
template<int IS_F32>
__device__ __forceinline__ void split_body(
    const int* __restrict__ src, const int* __restrict__ dst,
    const int* __restrict__ rel, const void* __restrict__ norm_raw,
    int* __restrict__ gcur, unsigned long long* __restrict__ R,
    int* hist, int* curs)
{
    const int blk = blockIdx.x;
    for (int i = threadIdx.x; i < NCB; i += 256) hist[i] = 0;
    __syncthreads();
    const int e0 = blk * P1_CHUNK;
    for (int i = threadIdx.x; i < P1_CHUNK; i += 256) {
        int e = e0 + i;
        if (e < N_EDGES) atomicAdd(&hist[dst[e] >> CB_SH], 1);
    }
    __syncthreads();
    for (int b = threadIdx.x; b < NCB; b += 256) {
        int c = hist[b];
        if (c > 0) {
            int s = atomicAdd(&gcur[b], c);
            if (s + c > CB_R_ARENA) s = CB_R_ARENA - c;   // OOB guard
            curs[b] = b * CB_R_ARENA + s;
        }
    }
    __syncthreads();
    for (int i = threadIdx.x; i < P1_CHUNK; i += 256) {
        int e = e0 + i;
        if (e >= N_EDGES) continue;
        int d = dst[e];
        int pos = atomicAdd(&curs[d >> CB_SH], 1);
        unsigned short nb = f2bfbits(ldx<IS_F32>(norm_raw, e));
        unsigned long long rec =
              (unsigned long long)(d & 127)
            | ((unsigned long long)(unsigned)src[e] << 8)
            | ((unsigned long long)(unsigned)rel[e] << 24)
            | ((unsigned long long)nb << 32);
        R[pos] = rec;
    }
}

__global__ __launch_bounds__(256) void k_split_prep(
    const int* __restrict__ src, const int* __restrict__ dst,
    const int* __restrict__ rel, const void* __restrict__ norm_raw,
    int* __restrict__ gcur, unsigned long long* __restrict__ R,
    const void* __restrict__ h_raw, const void* __restrict__ w_raw,
    unsigned short* __restrict__ hbf, unsigned short* __restrict__ Wswz,
    const int* __restrict__ flag)
{
    __shared__ int hist[NCB];
    __shared__ int curs[NCB];
    const int blk = blockIdx.x;
    if (blk < P1_GRID) {
        if (*flag) split_body<1>(src, dst, rel, norm_raw, gcur, R, hist, curs);
        else       split_body<0>(src, dst, rel, norm_raw, gcur, R, hist, curs);
    } else {
        const int f = *flag;
        const int blk2 = blk - P1_GRID;
        if (blk2 < PREP_HBLK) {
            const int x = threadIdx.x & 15, rl = threadIdx.x >> 4;
            const int row = blk2 * 16 + rl;
            const size_t rb = (size_t)row * 64;
            ushort4v o;
            if (f) {
                const float* hf = (const float*)h_raw;
                o[0] = f2bfbits(hf[rb + x]);
                o[1] = f2bfbits(hf[rb + x + 16]);
                o[2] = f2bfbits(hf[rb + x + 32]);
                o[3] = f2bfbits(hf[rb + x + 48]);
            } else {
                const unsigned short* hr = (const unsigned short*)h_raw;
                o[0] = hr[rb + x];
                o[1] = hr[rb + x + 16];
                o[2] = hr[rb + x + 32];
                o[3] = hr[rb + x + 48];
            }
            *(ushort4v*)(hbf + rb + 4 * x) = o;
        } else {
            int rel2 = blk2 - PREP_HBLK;
            for (int idx = threadIdx.x; idx < 4096; idx += 256) {
                int d = idx >> 6, o = idx & 63;
                float wv = f ? ((const float*)w_raw)[(size_t)((rel2 << 6) + d) * 64 + o]
                             : bfbits2f(((const unsigned short*)w_raw)[(size_t)((rel2 << 6) + d) * 64 + o]);
                int c = d >> 5, q = (d >> 3) & 3, j = d & 7;
                Wswz[(size_t)rel2 * 5120 + ((c << 6) + o) * 40 + q * 8 + j] = f2bfbits(wv);
            }
        }
    }
}

// ---------------------------------------------------------------------------
// K_FUSE3: fine + fused2 merged. One block per coarse bucket, 512 threads.
// Phase A: bin the cb's R run into 128 compact LDS bins (hist -> 2-wave
//   shfl scan with align-8 starts -> LDS place). No global packed arena,
//   no pad writes — partial chunks masked in Phase B.
// Phase B: wave w computes tile cb*8+w (all 16 rels): metadata from LDS
//   (broadcast ds_reads), permuted 8-B hbf gathers (R10-proven), selector
//   MFMA (R4-proven), s@W MFMA (k1-proven swizzle), relu store.
// ---------------------------------------------------------------------------
#define MFMA_BF16 __builtin_amdgcn_mfma_f32_16x16x32_bf16

__global__ __launch_bounds__(512) void k_fuse3(
    const int* __restrict__ gcur,
    const unsigned long long* __restrict__ R,
    const unsigned short* __restrict__ hbf,
    const unsigned short* __restrict__ Wswz,
    void* __restrict__ out, const int* __restrict__ flag)
{
    __shared__ unsigned pkL[LBIN];                     // 24.3 KB
    __shared__ unsigned short nrmL[LBIN];              // 12.2 KB
    __shared__ int cnt[128], sbl[128], cur[128];
    __shared__ int tot0s;
    __shared__ __align__(16) unsigned short sbuf[8][16 * 72];   // 18.4 KB

    const int tid = threadIdx.x, cb = blockIdx.x;
    const int wave = tid >> 6, lane = tid & 63;
    const int n15 = lane & 15, quad = lane >> 4;

    if (tid < 128) { cnt[tid] = 0; cur[tid] = 0; }
    __syncthreads();

    const int c0  = cb * CB_R_ARENA;
    const int run = min(gcur[cb], CB_R_ARENA);

    // --- A1: histogram 128 fine bins (bin = rel*8 + tile_local) ---
    for (int i = tid; i < run; i += 512) {
        unsigned long long rec = R[c0 + i];
        int bin = (int)((rec >> 24) & 15) * 8 + (int)((rec >> 4) & 7);
        atomicAdd(&cnt[bin], 1);
    }
    __syncthreads();

    // --- A2: exclusive scan of align8(cnt) -> sbl (2-wave shfl, proven) ---
    if (tid < 64) {
        int c = (cnt[tid] + 7) & ~7, incl = c;
#pragma unroll
        for (int off = 1; off < 64; off <<= 1) {
            int t = __shfl_up(incl, off, 64);
            if (tid >= off) incl += t;
        }
        sbl[tid] = incl - c;
        if (tid == 63) tot0s = incl;
    }
    __syncthreads();
    if (tid >= 64 && tid < 128) {
        int l2 = tid - 64;
        int c = (cnt[tid] + 7) & ~7, incl = c;
#pragma unroll
        for (int off = 1; off < 64; off <<= 1) {
            int t = __shfl_up(incl, off, 64);
            if (l2 >= off) incl += t;
        }
        sbl[tid] = tot0s + incl - c;
    }
    __syncthreads();

    // --- A3: place into compact LDS bins ---
    for (int i = tid; i < run; i += 512) {
        unsigned long long rec = R[c0 + i];
        int bin = (int)((rec >> 24) & 15) * 8 + (int)((rec >> 4) & 7);
        int pos = sbl[bin] + atomicAdd(&cur[bin], 1);
        pkL[pos]  = (unsigned)rec & 0x00FFFF0Fu;   // (dst&15) | (src<<8)
        nrmL[pos] = (unsigned short)(rec >> 32);
    }
    __syncthreads();

    // --- Phase B: wave w -> tile cb*8+w, all 16 rels ---
    const int tile = cb * 8 + wave;

    float4v ac0 = {0.f,0.f,0.f,0.f}, ac1 = {0.f,0.f,0.f,0.f};
    float4v ac2 = {0.f,0.f,0.f,0.f}, ac3 = {0.f,0.f,0.f,0.f};
    unsigned short* sb_ = &sbuf[wave][0];

    for (int r = 0; r < NREL; ++r) {
        const int bin = r * 8 + wave;
        const int bb = sbl[bin], bc = cnt[bin];
        if (bc == 0) continue;
        const int nch = (bc + 31) >> 5;

        float4v s0 = {0.f,0.f,0.f,0.f}, s1 = {0.f,0.f,0.f,0.f};
        float4v s2 = {0.f,0.f,0.f,0.f}, s3 = {0.f,0.f,0.f,0.f};

        for (int c = 0; c < nch; ++c) {
            const int base = bb + (c << 5) + (quad << 3);
            const int rem  = bc - ((c << 5) + (quad << 3));
            // broadcast LDS reads: 8 edges of this quad
            const uint4 pa = *(const uint4*)&pkL[base];
            const uint4 pb = *(const uint4*)&pkL[base + 4];
            const ushort4v na = *(const ushort4v*)&nrmL[base];
            const ushort4v nb = *(const ushort4v*)&nrmL[base + 4];

            // guarded srows (garbage pk beyond bc must not address OOB)
            const unsigned r0s = (rem > 0) ? (pa.x >> 8) : 0u;
            const unsigned r1s = (rem > 1) ? (pa.y >> 8) : 0u;
            const unsigned r2s = (rem > 2) ? (pa.z >> 8) : 0u;
            const unsigned r3s = (rem > 3) ? (pa.w >> 8) : 0u;
            const unsigned r4s = (rem > 4) ? (pb.x >> 8) : 0u;
            const unsigned r5s = (rem > 5) ? (pb.y >> 8) : 0u;
            const unsigned r6s = (rem > 6) ? (pb.z >> 8) : 0u;
            const unsigned r7s = (rem > 7) ? (pb.w >> 8) : 0u;

            const int co = 4 * n15;
            ushort4v v0 = *(const ushort4v*)(hbf + (size_t)r0s * 64 + co);
            ushort4v v1 = *(const ushort4v*)(hbf + (size_t)r1s * 64 + co);
            ushort4v v2 = *(const ushort4v*)(hbf + (size_t)r2s * 64 + co);
            ushort4v v3 = *(const ushort4v*)(hbf + (size_t)r3s * 64 + co);
            ushort4v v4 = *(const ushort4v*)(hbf + (size_t)r4s * 64 + co);
            ushort4v v5 = *(const ushort4v*)(hbf + (size_t)r5s * 64 + co);
            ushort4v v6 = *(const ushort4v*)(hbf + (size_t)r6s * 64 + co);
            ushort4v v7 = *(const ushort4v*)(hbf + (size_t)r7s * 64 + co);

            short8 av;
            av[0] = (rem > 0 && (int)(pa.x & 15u) == n15) ? (short)na[0] : (short)0;
            av[1] = (rem > 1 && (int)(pa.y & 15u) == n15) ? (short)na[1] : (short)0;
            av[2] = (rem > 2 && (int)(pa.z & 15u) == n15) ? (short)na[2] : (short)0;
            av[3] = (rem > 3 && (int)(pa.w & 15u) == n15) ? (short)na[3] : (short)0;
            av[4] = (rem > 4 && (int)(pb.x & 15u) == n15) ? (short)nb[0] : (short)0;
            av[5] = (rem > 5 && (int)(pb.y & 15u) == n15) ? (short)nb[1] : (short)0;
            av[6] = (rem > 6 && (int)(pb.z & 15u) == n15) ? (short)nb[2] : (short)0;
            av[7] = (rem > 7 && (int)(pb.w & 15u) == n15) ? (short)nb[3] : (short)0;

#define BV_MFMA(S, K) \
            { short8 bv; \
              bv[0] = (short)v0[K]; bv[1] = (short)v1[K]; \
              bv[2] = (short)v2[K]; bv[3] = (short)v3[K]; \
              bv[4] = (short)v4[K]; bv[5] = (short)v5[K]; \
              bv[6] = (short)v6[K]; bv[7] = (short)v7[K]; \
              S = MFMA_BF16(av, bv, S, 0, 0, 0); }

            BV_MFMA(s0, 0)
            BV_MFMA(s1, 1)
            BV_MFMA(s2, 2)
            BV_MFMA(s3, 3)
#undef BV_MFMA
        }

        // repack s (C layout: row=quad*4+i, col=t*16+n15) -> LDS row-major
#pragma unroll
        for (int i = 0; i < 4; ++i) {
            sb_[(quad * 4 + i) * 72 +  0 + n15] = f2bfbits(s0[i]);
            sb_[(quad * 4 + i) * 72 + 16 + n15] = f2bfbits(s1[i]);
            sb_[(quad * 4 + i) * 72 + 32 + n15] = f2bfbits(s2[i]);
            sb_[(quad * 4 + i) * 72 + 48 + n15] = f2bfbits(s3[i]);
        }

        // A-frags: row=n15, k-chunk=quad (k1-proven layout)
        const short8 a0 = *(const short8*)(sb_ + n15 * 72 + quad * 8);
        const short8 a1 = *(const short8*)(sb_ + n15 * 72 + 32 + quad * 8);

        const unsigned short* wp = Wswz + (size_t)r * 5120;
        const short8 w00 = *(const short8*)(wp + ( 0 + n15) * 40 + quad * 8);
        const short8 w01 = *(const short8*)(wp + (16 + n15) * 40 + quad * 8);
        const short8 w02 = *(const short8*)(wp + (32 + n15) * 40 + quad * 8);
        const short8 w03 = *(const short8*)(wp + (48 + n15) * 40 + quad * 8);
        const short8 w10 = *(const short8*)(wp + (64 + n15) * 40 + quad * 8);
        const short8 w11 = *(const short8*)(wp + (80 + n15) * 40 + quad * 8);
        const short8 w12 = *(const short8*)(wp + (96 + n15) * 40 + quad * 8);
        const short8 w13 = *(const short8*)(wp + (112 + n15) * 40 + quad * 8);

        ac0 = MFMA_BF16(a0, w00, ac0, 0, 0, 0);
        ac1 = MFMA_BF16(a0, w01, ac1, 0, 0, 0);
        ac2 = MFMA_BF16(a0, w02, ac2, 0, 0, 0);
        ac3 = MFMA_BF16(a0, w03, ac3, 0, 0, 0);
        ac0 = MFMA_BF16(a1, w10, ac0, 0, 0, 0);
        ac1 = MFMA_BF16(a1, w11, ac1, 0, 0, 0);
        ac2 = MFMA_BF16(a1, w12, ac2, 0, 0, 0);
        ac3 = MFMA_BF16(a1, w13, ac3, 0, 0, 0);
    }

    if (tile < NTILE) {
        const int node0 = tile << 4;
        const int f = *flag;
#define STORE_T(AC, T) \
        { \
            _Pragma("unroll") \
            for (int i = 0; i < 4; ++i) { \
                float rv = fmaxf(AC[i], 0.f); \
                size_t ob = (size_t)(node0 + quad * 4 + i) * 64 + (T) * 16 + n15; \
                if (f) ((float*)out)[ob] = rv; \
                else   ((unsigned short*)out)[ob] = f2bfbits(rv); \
            } \
        }
        STORE_T(ac0, 0)
        STORE_T(ac1, 1)
        STORE_T(ac2, 2)
        STORE_T(ac3, 3)
#undef STORE_T
    }
}

// ---------------------------------------------------------------------------
extern "C" void kernel_launch(void* const* d_in, const int* in_sizes, int n_in,
                              void* d_out, int out_size, void* d_ws, size_t ws_size,
                              hipStream_t stream)
{
    const void* h      = d_in[0];
    const void* weight = d_in[1];
    const void* norm   = d_in[2];
    const int* src = (const int*)d_in[3];
    const int* dst = (const int*)d_in[4];
    const int* rel = (const int*)d_in[5];

    char* w = (char*)d_ws;
    int* flag = (int*)w;                        w += 256;
    int* gcur = (int*)w;                        w += (NCB * 4 + 255) / 256 * 256;
    unsigned long long* R = (unsigned long long*)w;  w += (size_t)NCB * CB_R_ARENA * 8;
    unsigned short* hbf = (unsigned short*)w;   w += (size_t)N_NODES * DIM * 2;
    unsigned short* Wswz = (unsigned short*)w;  w += (size_t)NREL * 5120 * 2;

    k_detect<<<1, 1024, 0, stream>>>((const float*)norm, flag, gcur);

    k_split_prep<<<P1_GRID + PREP_HBLK + NREL, 256, 0, stream>>>(
        src, dst, rel, norm, gcur, R, h, weight, hbf, Wswz, flag);

    k_fuse3<<<NCB, 512, 0, stream>>>(gcur, R, hbf, Wswz, d_out, flag);
}

// Round 13
// 170.322 us; speedup vs baseline: 1.2551x; 1.0584x over previous
//
#include <hip/hip_runtime.h>
#include <hip/hip_bf16.h>

#define N_NODES 50000
#define N_EDGES 1600000
#define NREL    16
#define DIM     64

#define NTILE   3125          // 50000/16

#define CB_SH   7             // coarse bucket = dst>>7 (128 dsts)
#define NCB     391           // ceil(50000/128)
#define P1_CHUNK 2048
#define P1_GRID  782          // ceil(1.6M/2048)

#define CB_R_ARENA 5120       // R slots per coarse bucket (mean 4092 + 16 sigma)
#define LBIN    6080          // LDS bin arena: 5120 + 128*7 align8 + 31 overread
#define PREP_HBLK 3125        // 3.2M h elems / 1024 per block

typedef __attribute__((ext_vector_type(8))) short short8;
typedef __attribute__((ext_vector_type(4))) float float4v;
typedef __attribute__((ext_vector_type(4))) unsigned short ushort4v;

template<int IS_F32>
__device__ __forceinline__ float ldx(const void* p, size_t i) {
    if (IS_F32) {
        return ((const float*)p)[i];
    } else {
        unsigned short u = ((const unsigned short*)p)[i];
        return __uint_as_float(((unsigned)u) << 16);
    }
}

__device__ __forceinline__ float bfbits2f(unsigned short u) {
    return __uint_as_float(((unsigned)u) << 16);
}

__device__ __forceinline__ unsigned short f2bfbits(float v) {
    __hip_bfloat16 b = __float2bfloat16(v);
    unsigned short us; __builtin_memcpy(&us, &b, 2);
    return us;
}

// ---------------------------------------------------------------------------
// Dtype detector (proven) + gcur zeroing.
// ---------------------------------------------------------------------------
__global__ __launch_bounds__(1024) void k_detect(
    const float* __restrict__ norm_f, int* __restrict__ flag,
    int* __restrict__ gcur)
{
    __shared__ int sbad;
    if (threadIdx.x == 0) sbad = 0;
    if (threadIdx.x < NCB) gcur[threadIdx.x] = 0;
    __syncthreads();
    float v = norm_f[threadIdx.x];
    int bad = (v != v || fabsf(v) > 1e3f) ? 1 : 0;
    if (bad) atomicOr(&sbad, 1);
    __syncthreads();
    if (threadIdx.x == 0) *flag = sbad ? 0 : 1;
}

// ---------------------------------------------------------------------------
// SPLIT+PREP v2: R write now wave-coalesced via block-local LDS staging.
// Evidence (R12): consecutive lanes previously wrote 8-B recs to ~64
// distinct cache lines per store instruction (~1.6M scattered line ops —
// same ~50G lines/s wall as the gather kernels). Now records are placed
// bin-sorted into LDS, then copied out linearly: slot i -> gstart[bin] +
// (i - lstart[bin]); consecutive lanes in a bin's run hit consecutive
// addresses. cb is stashed in rec bits [56:48] (fuse3 ignores bits >47).
// dst values are kept in registers from the hist pass (chunk = 8 x 256).
// ---------------------------------------------------------------------------
template<int IS_F32>
__device__ __forceinline__ void split_body(
    const int* __restrict__ src, const int* __restrict__ dst,
    const int* __restrict__ rel, const void* __restrict__ norm_raw,
    int* __restrict__ gcur, unsigned long long* __restrict__ R,
    unsigned long long* stage, int* hist, int* lstart, int* gstart,
    int* lcur, int* totS)
{
    const int blk = blockIdx.x;
    const int tid = threadIdx.x;
    for (int i = tid; i < NCB; i += 256) { hist[i] = 0; lcur[i] = 0; }
    __syncthreads();

    const int e0 = blk * P1_CHUNK;
    int dreg[8];
    // phase 1: histogram (dst kept in registers)
#pragma unroll
    for (int k = 0; k < 8; ++k) {
        int e = e0 + k * 256 + tid;
        int d = (e < N_EDGES) ? dst[e] : -1;
        dreg[k] = d;
        if (d >= 0) atomicAdd(&hist[d >> CB_SH], 1);
    }
    __syncthreads();

    // phase 1b: wave-0 exclusive scan hist -> lstart
    if (tid < 64) {
        int carry = 0;
        for (int chunk = 0; chunk < (NCB + 63) / 64; ++chunk) {
            int i = chunk * 64 + tid;
            int c = (i < NCB) ? hist[i] : 0;
            int incl = c;
#pragma unroll
            for (int off = 1; off < 64; off <<= 1) {
                int t = __shfl_up(incl, off, 64);
                if (tid >= off) incl += t;
            }
            if (i < NCB) lstart[i] = carry + incl - c;
            carry += __shfl(incl, 63, 64);
        }
        if (tid == 0) *totS = carry;
    }
    __syncthreads();

    // phase 2: global reservation (one device atomic per non-empty bin)
    for (int b = tid; b < NCB; b += 256) {
        int c = hist[b];
        if (c > 0) {
            int s = atomicAdd(&gcur[b], c);
            if (s + c > CB_R_ARENA) s = CB_R_ARENA - c;   // OOB guard
            gstart[b] = b * CB_R_ARENA + s;
        }
    }
    __syncthreads();

    // phase 3: place records bin-sorted into LDS staging
#pragma unroll
    for (int k = 0; k < 8; ++k) {
        int e = e0 + k * 256 + tid;
        int d = dreg[k];
        if (d < 0) continue;
        int cb = d >> CB_SH;
        int pos = lstart[cb] + atomicAdd(&lcur[cb], 1);
        unsigned short nb = f2bfbits(ldx<IS_F32>(norm_raw, e));
        unsigned long long rec =
              (unsigned long long)(d & 127)
            | ((unsigned long long)(unsigned)src[e] << 8)
            | ((unsigned long long)(unsigned)rel[e] << 24)
            | ((unsigned long long)nb << 32)
            | ((unsigned long long)(unsigned)cb << 48);
        stage[pos] = rec;
    }
    __syncthreads();

    // phase 4: coalesced copy-out (runs of a bin are contiguous both sides)
    const int tot = *totS;
    for (int i = tid; i < tot; i += 256) {
        unsigned long long rec = stage[i];
        int bin = (int)((rec >> 48) & 511u);
        R[gstart[bin] + (i - lstart[bin])] = rec;
    }
}

__global__ __launch_bounds__(256) void k_split_prep(
    const int* __restrict__ src, const int* __restrict__ dst,
    const int* __restrict__ rel, const void* __restrict__ norm_raw,
    int* __restrict__ gcur, unsigned long long* __restrict__ R,
    const void* __restrict__ h_raw, const void* __restrict__ w_raw,
    unsigned short* __restrict__ hbf, unsigned short* __restrict__ Wswz,
    const int* __restrict__ flag)
{
    __shared__ unsigned long long stage[P1_CHUNK];   // 16 KB
    __shared__ int hist[NCB], lstart[NCB], gstart[NCB], lcur[NCB];
    __shared__ int totS;
    const int blk = blockIdx.x;
    if (blk < P1_GRID) {
        if (*flag) split_body<1>(src, dst, rel, norm_raw, gcur, R,
                                 stage, hist, lstart, gstart, lcur, &totS);
        else       split_body<0>(src, dst, rel, norm_raw, gcur, R,
                                 stage, hist, lstart, gstart, lcur, &totS);
    } else {
        const int f = *flag;
        const int blk2 = blk - P1_GRID;
        if (blk2 < PREP_HBLK) {
            const int x = threadIdx.x & 15, rl = threadIdx.x >> 4;
            const int row = blk2 * 16 + rl;
            const size_t rb = (size_t)row * 64;
            ushort4v o;
            if (f) {
                const float* hf = (const float*)h_raw;
                o[0] = f2bfbits(hf[rb + x]);
                o[1] = f2bfbits(hf[rb + x + 16]);
                o[2] = f2bfbits(hf[rb + x + 32]);
                o[3] = f2bfbits(hf[rb + x + 48]);
            } else {
                const unsigned short* hr = (const unsigned short*)h_raw;
                o[0] = hr[rb + x];
                o[1] = hr[rb + x + 16];
                o[2] = hr[rb + x + 32];
                o[3] = hr[rb + x + 48];
            }
            *(ushort4v*)(hbf + rb + 4 * x) = o;
        } else {
            int rel2 = blk2 - PREP_HBLK;
            for (int idx = threadIdx.x; idx < 4096; idx += 256) {
                int d = idx >> 6, o = idx & 63;
                float wv = f ? ((const float*)w_raw)[(size_t)((rel2 << 6) + d) * 64 + o]
                             : bfbits2f(((const unsigned short*)w_raw)[(size_t)((rel2 << 6) + d) * 64 + o]);
                int c = d >> 5, q = (d >> 3) & 3, j = d & 7;
                Wswz[(size_t)rel2 * 5120 + ((c << 6) + o) * 40 + q * 8 + j] = f2bfbits(wv);
            }
        }
    }
}

// ---------------------------------------------------------------------------
// K_FUSE3 (proven R12, byte-identical): fine + fused2 merged. One block per
// coarse bucket, 512 threads. Phase A: bin the cb's R run into 128 compact
// LDS bins. Phase B: wave w computes tile cb*8+w (all 16 rels): metadata
// from LDS, permuted 8-B hbf gathers, selector MFMA, s@W MFMA, relu store.
// NOTE: rec bits >47 (cb tag from split v2) are ignored by all extractions.
// ---------------------------------------------------------------------------
#define MFMA_BF16 __builtin_amdgcn_mfma_f32_16x16x32_bf16

__global__ __launch_bounds__(512) void k_fuse3(
    const int* __restrict__ gcur,
    const unsigned long long* __restrict__ R,
    const unsigned short* __restrict__ hbf,
    const unsigned short* __restrict__ Wswz,
    void* __restrict__ out, const int* __restrict__ flag)
{
    __shared__ unsigned pkL[LBIN];                     // 24.3 KB
    __shared__ unsigned short nrmL[LBIN];              // 12.2 KB
    __shared__ int cnt[128], sbl[128], cur[128];
    __shared__ int tot0s;
    __shared__ __align__(16) unsigned short sbuf[8][16 * 72];   // 18.4 KB

    const int tid = threadIdx.x, cb = blockIdx.x;
    const int wave = tid >> 6, lane = tid & 63;
    const int n15 = lane & 15, quad = lane >> 4;

    if (tid < 128) { cnt[tid] = 0; cur[tid] = 0; }
    __syncthreads();

    const int c0  = cb * CB_R_ARENA;
    const int run = min(gcur[cb], CB_R_ARENA);

    // --- A1: histogram 128 fine bins (bin = rel*8 + tile_local) ---
    for (int i = tid; i < run; i += 512) {
        unsigned long long rec = R[c0 + i];
        int bin = (int)((rec >> 24) & 15) * 8 + (int)((rec >> 4) & 7);
        atomicAdd(&cnt[bin], 1);
    }
    __syncthreads();

    // --- A2: exclusive scan of align8(cnt) -> sbl (2-wave shfl, proven) ---
    if (tid < 64) {
        int c = (cnt[tid] + 7) & ~7, incl = c;
#pragma unroll
        for (int off = 1; off < 64; off <<= 1) {
            int t = __shfl_up(incl, off, 64);
            if (tid >= off) incl += t;
        }
        sbl[tid] = incl - c;
        if (tid == 63) tot0s = incl;
    }
    __syncthreads();
    if (tid >= 64 && tid < 128) {
        int l2 = tid - 64;
        int c = (cnt[tid] + 7) & ~7, incl = c;
#pragma unroll
        for (int off = 1; off < 64; off <<= 1) {
            int t = __shfl_up(incl, off, 64);
            if (l2 >= off) incl += t;
        }
        sbl[tid] = tot0s + incl - c;
    }
    __syncthreads();

    // --- A3: place into compact LDS bins ---
    for (int i = tid; i < run; i += 512) {
        unsigned long long rec = R[c0 + i];
        int bin = (int)((rec >> 24) & 15) * 8 + (int)((rec >> 4) & 7);
        int pos = sbl[bin] + atomicAdd(&cur[bin], 1);
        pkL[pos]  = (unsigned)rec & 0x00FFFF0Fu;   // (dst&15) | (src<<8)
        nrmL[pos] = (unsigned short)(rec >> 32);
    }
    __syncthreads();

    // --- Phase B: wave w -> tile cb*8+w, all 16 rels ---
    const int tile = cb * 8 + wave;

    float4v ac0 = {0.f,0.f,0.f,0.f}, ac1 = {0.f,0.f,0.f,0.f};
    float4v ac2 = {0.f,0.f,0.f,0.f}, ac3 = {0.f,0.f,0.f,0.f};
    unsigned short* sb_ = &sbuf[wave][0];

    for (int r = 0; r < NREL; ++r) {
        const int bin = r * 8 + wave;
        const int bb = sbl[bin], bc = cnt[bin];
        if (bc == 0) continue;
        const int nch = (bc + 31) >> 5;

        float4v s0 = {0.f,0.f,0.f,0.f}, s1 = {0.f,0.f,0.f,0.f};
        float4v s2 = {0.f,0.f,0.f,0.f}, s3 = {0.f,0.f,0.f,0.f};

        for (int c = 0; c < nch; ++c) {
            const int base = bb + (c << 5) + (quad << 3);
            const int rem  = bc - ((c << 5) + (quad << 3));
            // broadcast LDS reads: 8 edges of this quad
            const uint4 pa = *(const uint4*)&pkL[base];
            const uint4 pb = *(const uint4*)&pkL[base + 4];
            const ushort4v na = *(const ushort4v*)&nrmL[base];
            const ushort4v nb = *(const ushort4v*)&nrmL[base + 4];

            // guarded srows (garbage pk beyond bc must not address OOB)
            const unsigned r0s = (rem > 0) ? (pa.x >> 8) : 0u;
            const unsigned r1s = (rem > 1) ? (pa.y >> 8) : 0u;
            const unsigned r2s = (rem > 2) ? (pa.z >> 8) : 0u;
            const unsigned r3s = (rem > 3) ? (pa.w >> 8) : 0u;
            const unsigned r4s = (rem > 4) ? (pb.x >> 8) : 0u;
            const unsigned r5s = (rem > 5) ? (pb.y >> 8) : 0u;
            const unsigned r6s = (rem > 6) ? (pb.z >> 8) : 0u;
            const unsigned r7s = (rem > 7) ? (pb.w >> 8) : 0u;

            const int co = 4 * n15;
            ushort4v v0 = *(const ushort4v*)(hbf + (size_t)r0s * 64 + co);
            ushort4v v1 = *(const ushort4v*)(hbf + (size_t)r1s * 64 + co);
            ushort4v v2 = *(const ushort4v*)(hbf + (size_t)r2s * 64 + co);
            ushort4v v3 = *(const ushort4v*)(hbf + (size_t)r3s * 64 + co);
            ushort4v v4 = *(const ushort4v*)(hbf + (size_t)r4s * 64 + co);
            ushort4v v5 = *(const ushort4v*)(hbf + (size_t)r5s * 64 + co);
            ushort4v v6 = *(const ushort4v*)(hbf + (size_t)r6s * 64 + co);
            ushort4v v7 = *(const ushort4v*)(hbf + (size_t)r7s * 64 + co);

            short8 av;
            av[0] = (rem > 0 && (int)(pa.x & 15u) == n15) ? (short)na[0] : (short)0;
            av[1] = (rem > 1 && (int)(pa.y & 15u) == n15) ? (short)na[1] : (short)0;
            av[2] = (rem > 2 && (int)(pa.z & 15u) == n15) ? (short)na[2] : (short)0;
            av[3] = (rem > 3 && (int)(pa.w & 15u) == n15) ? (short)na[3] : (short)0;
            av[4] = (rem > 4 && (int)(pb.x & 15u) == n15) ? (short)nb[0] : (short)0;
            av[5] = (rem > 5 && (int)(pb.y & 15u) == n15) ? (short)nb[1] : (short)0;
            av[6] = (rem > 6 && (int)(pb.z & 15u) == n15) ? (short)nb[2] : (short)0;
            av[7] = (rem > 7 && (int)(pb.w & 15u) == n15) ? (short)nb[3] : (short)0;

#define BV_MFMA(S, K) \
            { short8 bv; \
              bv[0] = (short)v0[K]; bv[1] = (short)v1[K]; \
              bv[2] = (short)v2[K]; bv[3] = (short)v3[K]; \
              bv[4] = (short)v4[K]; bv[5] = (short)v5[K]; \
              bv[6] = (short)v6[K]; bv[7] = (short)v7[K]; \
              S = MFMA_BF16(av, bv, S, 0, 0, 0); }

            BV_MFMA(s0, 0)
            BV_MFMA(s1, 1)
            BV_MFMA(s2, 2)
            BV_MFMA(s3, 3)
#undef BV_MFMA
        }

        // repack s (C layout: row=quad*4+i, col=t*16+n15) -> LDS row-major
#pragma unroll
        for (int i = 0; i < 4; ++i) {
            sb_[(quad * 4 + i) * 72 +  0 + n15] = f2bfbits(s0[i]);
            sb_[(quad * 4 + i) * 72 + 16 + n15] = f2bfbits(s1[i]);
            sb_[(quad * 4 + i) * 72 + 32 + n15] = f2bfbits(s2[i]);
            sb_[(quad * 4 + i) * 72 + 48 + n15] = f2bfbits(s3[i]);
        }

        // A-frags: row=n15, k-chunk=quad (k1-proven layout)
        const short8 a0 = *(const short8*)(sb_ + n15 * 72 + quad * 8);
        const short8 a1 = *(const short8*)(sb_ + n15 * 72 + 32 + quad * 8);

        const unsigned short* wp = Wswz + (size_t)r * 5120;
        const short8 w00 = *(const short8*)(wp + ( 0 + n15) * 40 + quad * 8);
        const short8 w01 = *(const short8*)(wp + (16 + n15) * 40 + quad * 8);
        const short8 w02 = *(const short8*)(wp + (32 + n15) * 40 + quad * 8);
        const short8 w03 = *(const short8*)(wp + (48 + n15) * 40 + quad * 8);
        const short8 w10 = *(const short8*)(wp + (64 + n15) * 40 + quad * 8);
        const short8 w11 = *(const short8*)(wp + (80 + n15) * 40 + quad * 8);
        const short8 w12 = *(const short8*)(wp + (96 + n15) * 40 + quad * 8);
        const short8 w13 = *(const short8*)(wp + (112 + n15) * 40 + quad * 8);

        ac0 = MFMA_BF16(a0, w00, ac0, 0, 0, 0);
        ac1 = MFMA_BF16(a0, w01, ac1, 0, 0, 0);
        ac2 = MFMA_BF16(a0, w02, ac2, 0, 0, 0);
        ac3 = MFMA_BF16(a0, w03, ac3, 0, 0, 0);
        ac0 = MFMA_BF16(a1, w10, ac0, 0, 0, 0);
        ac1 = MFMA_BF16(a1, w11, ac1, 0, 0, 0);
        ac2 = MFMA_BF16(a1, w12, ac2, 0, 0, 0);
        ac3 = MFMA_BF16(a1, w13, ac3, 0, 0, 0);
    }

    if (tile < NTILE) {
        const int node0 = tile << 4;
        const int f = *flag;
#define STORE_T(AC, T) \
        { \
            _Pragma("unroll") \
            for (int i = 0; i < 4; ++i) { \
                float rv = fmaxf(AC[i], 0.f); \
                size_t ob = (size_t)(node0 + quad * 4 + i) * 64 + (T) * 16 + n15; \
                if (f) ((float*)out)[ob] = rv; \
                else   ((unsigned short*)out)[ob] = f2bfbits(rv); \
            } \
        }
        STORE_T(ac0, 0)
        STORE_T(ac1, 1)
        STORE_T(ac2, 2)
        STORE_T(ac3, 3)
#undef STORE_T
    }
}

// ---------------------------------------------------------------------------
extern "C" void kernel_launch(void* const* d_in, const int* in_sizes, int n_in,
                              void* d_out, int out_size, void* d_ws, size_t ws_size,
                              hipStream_t stream)
{
    const void* h      = d_in[0];
    const void* weight = d_in[1];
    const void* norm   = d_in[2];
    const int* src = (const int*)d_in[3];
    const int* dst = (const int*)d_in[4];
    const int* rel = (const int*)d_in[5];

    char* w = (char*)d_ws;
    int* flag = (int*)w;                        w += 256;
    int* gcur = (int*)w;                        w += (NCB * 4 + 255) / 256 * 256;
    unsigned long long* R = (unsigned long long*)w;  w += (size_t)NCB * CB_R_ARENA * 8;
    unsigned short* hbf = (unsigned short*)w;   w += (size_t)N_NODES * DIM * 2;
    unsigned short* Wswz = (unsigned short*)w;  w += (size_t)NREL * 5120 * 2;

    k_detect<<<1, 1024, 0, stream>>>((const float*)norm, flag, gcur);

    k_split_prep<<<P1_GRID + PREP_HBLK + NREL, 256, 0, stream>>>(
        src, dst, rel, norm, gcur, R, h, weight, hbf, Wswz, flag);

    k_fuse3<<<NCB, 512, 0, stream>>>(gcur, R, hbf, Wswz, d_out, flag);
}